// Round 15
// baseline (11023.100 us; speedup 1.0000x reference)
//
#include <hip/hip_runtime.h>
#include <cstdint>
#include <cstddef>

typedef __bf16 bf16;
typedef __bf16 bf16x8 __attribute__((ext_vector_type(8)));
typedef __bf16 bf16x4 __attribute__((ext_vector_type(4)));
typedef float f32x4 __attribute__((ext_vector_type(4)));

#define NB 16
#define SS 2048
#define HH 12
#define NLL 12
#define MTOK (NB*SS)

#define BARRIER() do { asm volatile("" ::: "memory"); __builtin_amdgcn_s_barrier(); asm volatile("" ::: "memory"); } while (0)
#define VMCNT0()  asm volatile("s_waitcnt vmcnt(0)" ::: "memory")

// ---------------- async global->LDS (16B per lane) ----------------
__device__ __forceinline__ void load16_lds(const bf16* g, bf16* l) {
    __builtin_amdgcn_global_load_lds((const __attribute__((address_space(1))) void*)g,
                                     (__attribute__((address_space(3))) void*)l, 16, 0, 0);
}

// ---------------- diagnostic ----------------
__global__ void diag_k(float* out, float code) {
    if (threadIdx.x == 0 && blockIdx.x == 0) out[0] = code;
}

// ---------------- per-layer weight pack: f32 [K][N] -> bf16 [N][K] ----------------
__global__ __launch_bounds__(256) void packw_k(const float* __restrict__ wq, const float* __restrict__ wk,
                                               const float* __restrict__ wv, const float* __restrict__ wo,
                                               const float* __restrict__ w1, const float* __restrict__ w2,
                                               int l, bf16* qkvT_l, bf16* oT_l, bf16* w1T_l, bf16* w2T_l) {
    __shared__ float tile[32][33];
    int which = blockIdx.z;
    const float* srcs[6] = {wq, wk, wv, wo, w1, w2};
    const float* src = srcs[which] + (size_t)l * 589824;
    bf16* dst;
    if (which < 3)       dst = qkvT_l + (size_t)which * 589824;
    else if (which == 3) dst = oT_l;
    else if (which == 4) dst = w1T_l;
    else                 dst = w2T_l;
    int tx = threadIdx.x, ty = threadIdx.y;
    int bx = blockIdx.x, by = blockIdx.y;
#pragma unroll
    for (int j = 0; j < 4; ++j)
        tile[ty + j*8][tx] = src[(size_t)(by*32 + ty + j*8) * 768 + bx*32 + tx];
    __syncthreads();
#pragma unroll
    for (int j = 0; j < 4; ++j)
        dst[(size_t)(bx*32 + ty + j*8) * 768 + by*32 + tx] = (bf16)tile[tx][ty + j*8];
}

__global__ void packb_k(const float* __restrict__ bq, const float* __restrict__ bk,
                        const float* __restrict__ bv, float* bqkv) {
    int i = blockIdx.x * 256 + threadIdx.x;
    if (i >= NLL * 2304) return;
    int l = i / 2304, c = i % 2304;
    float v = (c < 768) ? bq[l*768 + c] : (c < 1536) ? bk[l*768 + c - 768] : bv[l*768 + c - 1536];
    bqkv[i] = v;
}

// ---------------- rope tables ----------------
__global__ void rope_k(float* cosT, float* sinT) {
    int i = blockIdx.x * 256 + threadIdx.x;  // S*64 total
    int s = i >> 6, j = i & 63, f = j & 31;
    float inv = powf(10000.f, -(float)(2*f) * (1.0f/64.0f));
    float ang = (float)s * inv;
    cosT[i] = cosf(ang);
    sinT[i] = sinf(ang);
}

// ---------------- embedding gather ----------------
__global__ __launch_bounds__(192) void embed_k(const int* __restrict__ idx, const float* __restrict__ emb,
                                               float* __restrict__ x, bf16* __restrict__ xb) {
    size_t tok = blockIdx.x;
    int t = threadIdx.x;
    int id = idx[tok];
    float4 v = *(const float4*)&emb[(size_t)id * 768 + t*4];
    *(float4*)&x[tok * 768 + t*4] = v;
    bf16x4 o; o[0] = (bf16)v.x; o[1] = (bf16)v.y; o[2] = (bf16)v.z; o[3] = (bf16)v.w;
    *(bf16x4*)&xb[tok * 768 + t*4] = o;
}

// ============ Fused QKV GEMM + rope + phi: 256x128 tile, BK=32, 48KB LDS, 2 blocks/CU ============
// Q/K tiles (bcol<1536): epilogue ropes C in-register (lane-local: partner d^32 = ni^2),
// stores roped bf16 to LDS (64-col swizzled rows), tiny MFMA [256x64]@[64x32] vs omega^T,
// relu(+mask) -> Qf/Kf. Q/K never touch HBM. V tiles: original LDS-transposed store.
__global__ __launch_bounds__(512, 4)
void gemmqkv_k(const bf16* __restrict__ A, const bf16* __restrict__ Bt,
               const float* __restrict__ bias,
               const float* __restrict__ cosT, const float* __restrict__ sinT,
               const float* __restrict__ omega_l, const int* __restrict__ mask,
               bf16* __restrict__ vout, bf16* __restrict__ Qf, bf16* __restrict__ Kf, int N) {
    const int K = 768;
    __shared__ bf16 sh[24576];                  // 48KB: As[2][8192] | Bs[2][4096]; epilogue reuse
    const int t = threadIdx.x;
    const int w = t >> 6, lane = t & 63;
    const int wr = w >> 1, wc = w & 1;          // 4M x 2N wave grid

    const int nx = gridDim.x;                   // 18
    const int L = blockIdx.y * nx + blockIdx.x;
    const int xcd = L & 7, bi = L >> 3;
    const int bcol = (bi % nx) * 128;
    const int brow = ((bi / nx) * 8 + xcd) * 256;

    const int srow = t >> 2;                    // 0..127
    const int scol = (((t & 3) * 16) ^ (((srow >> 1) & 3) << 4)) >> 1;

    auto stageA = [&](int s, int k0) {
        load16_lds(A + (size_t)(brow + srow)       * K + k0 + scol, &sh[s*8192 + t*8]);
        load16_lds(A + (size_t)(brow + 128 + srow) * K + k0 + scol, &sh[s*8192 + 4096 + t*8]);
    };
    auto stageB = [&](int s, int k0) {
        load16_lds(Bt + (size_t)(bcol + srow)      * K + k0 + scol, &sh[16384 + s*4096 + t*8]);
    };

    const int rowa = lane & 15, kg = lane >> 4;
    const int celem = ((kg * 16) ^ (((rowa >> 1) & 3) << 4)) >> 1;

    f32x4  acc[4][4] = {};
    bf16x8 af[4], bg[4];

    stageA(0, 0); stageB(0, 0);
    VMCNT0();
    BARRIER();

    for (int kt = 0; kt < 24; ++kt) {
        const int cur = kt & 1, nb = cur ^ 1;
        const int kn = (kt + 1) * 32;
        const bool st = (kt < 23);
#pragma unroll
        for (int mi = 0; mi < 4; ++mi)
            af[mi] = *(const bf16x8*)&sh[cur*8192 + (wr*64 + mi*16 + rowa)*32 + celem];
#pragma unroll
        for (int ni = 0; ni < 4; ++ni)
            bg[ni] = *(const bf16x8*)&sh[16384 + cur*4096 + (wc*64 + ni*16 + rowa)*32 + celem];
        if (st) { stageA(nb, kn); stageB(nb, kn); }
        BARRIER();
        __builtin_amdgcn_s_setprio(1);
#pragma unroll
        for (int mi = 0; mi < 4; ++mi)
#pragma unroll
            for (int ni = 0; ni < 4; ++ni)
                acc[mi][ni] = __builtin_amdgcn_mfma_f32_16x16x32_bf16(af[mi], bg[ni], acc[mi][ni], 0, 0, 0);
        __builtin_amdgcn_s_setprio(0);
        VMCNT0();
        BARRIER();
    }

    const int r0 = (lane >> 4) * 4, c0 = lane & 15;

    if (bcol >= 1536) {
        // ---- V epilogue: C via LDS (two 256x64 col-halves), coalesced 16B stores ----
        bf16* Cs = sh;
        const int ch = t & 7, rr = t >> 3;
#pragma unroll
        for (int h = 0; h < 2; ++h) {
            __syncthreads();
            if (wc == h) {
#pragma unroll
                for (int mi = 0; mi < 4; ++mi)
#pragma unroll
                    for (int ni = 0; ni < 4; ++ni) {
                        int col = bcol + wc * 64 + ni * 16 + c0;
                        float bv = bias[col];
#pragma unroll
                        for (int r = 0; r < 4; ++r)
                            Cs[(wr*64 + mi*16 + r0 + r) * 64 + ni*16 + c0] =
                                (bf16)(acc[mi][ni][r] + bv);
                    }
            }
            __syncthreads();
#pragma unroll
            for (int i = 0; i < 4; ++i) {
                int row = rr + i * 64;
                *(bf16x8*)&vout[(size_t)(brow + row) * N + bcol + h*64 + ch*8] =
                    *(const bf16x8*)&Cs[row * 64 + ch * 8];
            }
        }
        return;
    }

    // ---- Q/K fused rope + phi epilogue ----
    const int side = (bcol >= 768) ? 1 : 0;                 // 0=Q, 1=K
    const int head0 = (bcol - side * 768) >> 6;
    bf16* Cs  = sh;                                         // 256 rows x 64 elems (swizzled 128B rows)
    bf16* omT = sh + 16384;                                 // 32 rows x 64 elems (swizzled)

    __syncthreads();
    for (int i = t; i < 2048; i += 512) {                   // omega^T -> LDS (once)
        int f = i >> 6, d = i & 63;
        int byte = f * 128 + ((d * 2) ^ ((f & 7) << 4));
        *(bf16*)((char*)omT + byte) = (bf16)omega_l[d * 32 + f];
    }

    const int rsw2 = (rowa & 7) << 4;
    bf16* outp = side ? Kf : Qf;

#pragma unroll 1
    for (int h = 0; h < 2; ++h) {
        __syncthreads();
        if (wc == h) {
            // phase A: bias + rope (lane-local), write roped bf16 to swizzled LDS
            float bv[4];
#pragma unroll
            for (int ni = 0; ni < 4; ++ni) bv[ni] = bias[bcol + h*64 + ni*16 + c0];
#pragma unroll
            for (int mi = 0; mi < 4; ++mi)
#pragma unroll
                for (int r = 0; r < 4; ++r) {
                    int row = wr*64 + mi*16 + r0 + r;
                    int s = (brow + row) & (SS - 1);
                    const float* cp = cosT + s*64;
                    const float* sp = sinT + s*64;
                    float q[4];
#pragma unroll
                    for (int ni = 0; ni < 4; ++ni) q[ni] = acc[mi][ni][r] + bv[ni];
#pragma unroll
                    for (int ni = 0; ni < 4; ++ni) {
                        int d = ni*16 + c0;
                        float rv = q[ni]*cp[d] + (ni < 2 ? -q[ni^2] : q[ni^2]) * sp[d];
                        int byte = row*128 + ((d*2) ^ ((row & 7) << 4));
                        *(bf16*)((char*)Cs + byte) = (bf16)rv;
                    }
                }
        }
        __syncthreads();
        // phase B: phi MFMA [256x64]@[64x32]; wave w -> row-tiles {2w,2w+1}, both f-tiles
        f32x4 pac[2][2] = {};
#pragma unroll
        for (int ks = 0; ks < 2; ++ks) {
            const int cb = ks*64 + kg*16;
            bf16x8 paf[2], pbg[2];
#pragma unroll
            for (int j = 0; j < 2; ++j)
                paf[j] = *(const bf16x8*)&Cs[((w*2 + j)*16 + rowa)*64 + ((cb ^ rsw2) >> 1)];
#pragma unroll
            for (int ft = 0; ft < 2; ++ft)
                pbg[ft] = *(const bf16x8*)&omT[(ft*16 + rowa)*64 + ((cb ^ rsw2) >> 1)];
#pragma unroll
            for (int j = 0; j < 2; ++j)
#pragma unroll
                for (int ft = 0; ft < 2; ++ft)
                    pac[j][ft] = __builtin_amdgcn_mfma_f32_16x16x32_bf16(paf[j], pbg[ft], pac[j][ft], 0, 0, 0);
        }
        // phase C: relu (+mask for K), store to Qf/Kf
        const int head = head0 + h;
#pragma unroll
        for (int j = 0; j < 2; ++j)
#pragma unroll
            for (int r = 0; r < 4; ++r) {
                size_t tok = (size_t)brow + (w*2 + j)*16 + r0 + r;
                float m = side ? (float)mask[tok] : 1.f;
#pragma unroll
                for (int ft = 0; ft < 2; ++ft) {
                    float v = fmaxf(pac[j][ft][r], 0.f) * m;
                    outp[(tok*12 + head)*32 + ft*16 + c0] = (bf16)v;
                }
            }
    }
}

// ============ 128x128 GEMM, BK=64 + T2 swizzle + LDS-transposed epilogue (round-8 proven) ============
// MODE 0: +bias -> bf16; MODE 1: +bias, gelu -> bf16
template <int MODE>
__global__ __launch_bounds__(256)
void gemm128_k(const bf16* __restrict__ A, const bf16* __restrict__ Bt,
               const float* __restrict__ bias, bf16* __restrict__ outb, int N) {
    const int K = 768;
    __shared__ bf16 sh[16384];
    bf16* As = sh;
    bf16* Bs = sh + 8192;
    const int t = threadIdx.x;
    const int w = t >> 6, lane = t & 63;
    const int wr = w >> 1, wc = w & 1;

    const int nx = gridDim.x;
    const int L = blockIdx.y * nx + blockIdx.x;
    const int xcd = L & 7, bi = L >> 3;
    const int bcol = (bi % nx) * 128;
    const int brow = ((bi / nx) * 8 + xcd) * 128;

    const int srow = t >> 3;
    const int scol = (((t & 7) * 16) ^ ((srow & 7) << 4)) >> 1;
    const int rowa = lane & 15, kg = lane >> 4;
    const int rsw  = (rowa & 7) << 4;

    f32x4 acc[4][4] = {};

    for (int k0 = 0; k0 < K; k0 += 64) {
        __syncthreads();
#pragma unroll
        for (int j = 0; j < 4; ++j) {
            load16_lds(A  + (size_t)(brow + j*32 + srow) * K + k0 + scol, &As[j*2048 + t*8]);
            load16_lds(Bt + (size_t)(bcol + j*32 + srow) * K + k0 + scol, &Bs[j*2048 + t*8]);
        }
        __syncthreads();
        bf16x8 af[4][2], bg[4][2];
#pragma unroll
        for (int mi = 0; mi < 4; ++mi)
#pragma unroll
            for (int ks = 0; ks < 2; ++ks)
                af[mi][ks] = *(const bf16x8*)&As[(wr*64 + mi*16 + rowa)*64 + (((ks*64 + kg*16) ^ rsw) >> 1)];
#pragma unroll
        for (int ni = 0; ni < 4; ++ni)
#pragma unroll
            for (int ks = 0; ks < 2; ++ks)
                bg[ni][ks] = *(const bf16x8*)&Bs[(wc*64 + ni*16 + rowa)*64 + (((ks*64 + kg*16) ^ rsw) >> 1)];
#pragma unroll
        for (int mi = 0; mi < 4; ++mi)
#pragma unroll
            for (int ni = 0; ni < 4; ++ni)
#pragma unroll
                for (int ks = 0; ks < 2; ++ks)
                    acc[mi][ni] = __builtin_amdgcn_mfma_f32_16x16x32_bf16(af[mi][ks], bg[ni][ks], acc[mi][ni], 0, 0, 0);
    }

    __syncthreads();
    const int r0 = (lane >> 4) * 4, c0 = lane & 15;
#pragma unroll
    for (int mi = 0; mi < 4; ++mi)
#pragma unroll
        for (int ni = 0; ni < 4; ++ni) {
            int col = bcol + wc * 64 + ni * 16 + c0;
            float bv = bias[col];
#pragma unroll
            for (int r = 0; r < 4; ++r) {
                float v = acc[mi][ni][r] + bv;
                if (MODE == 1) v = 0.5f * v * (1.f + erff(v * 0.70710678118f));
                sh[(wr*64 + mi*16 + r0 + r) * 128 + wc*64 + ni*16 + c0] = (bf16)v;
            }
        }
    __syncthreads();
    const int ch = t & 15, rr = t >> 4;
#pragma unroll
    for (int i = 0; i < 8; ++i) {
        int row = rr + i * 16;
        *(bf16x8*)&outb[(size_t)(brow + row) * N + bcol + ch*8] =
            *(const bf16x8*)&sh[row * 128 + ch * 8];
    }
}

// ---------------- KV partial: per (b,h,chunk) sum_s Kf[s,f]*v[s,d]; also sum Kf ----------------
__global__ __launch_bounds__(256) void kvp_k(const bf16* __restrict__ Kf, const bf16* __restrict__ qkv,
                                             float* __restrict__ KVp, float* __restrict__ Ksp) {
    int ch = blockIdx.x, h = blockIdx.y, b = blockIdx.z;
    __shared__ float kts[64][32];
    __shared__ bf16 vts[64][64];
    int t = threadIdx.x;
    int fg = t & 15, dg = t >> 4;
    int f0 = fg * 2, d0 = dg * 4;
    float acc[8] = {};
    float ksm[2] = {};
    for (int s0 = ch * 256; s0 < ch * 256 + 256; s0 += 64) {
        __syncthreads();
        {
            int row = t >> 2, slot = t & 3;
            bf16x8 k8 = *(const bf16x8*)&Kf[((size_t)(b * SS + s0 + row) * 12 + h) * 32 + slot * 8];
#pragma unroll
            for (int e = 0; e < 8; ++e) kts[row][slot * 8 + e] = (float)k8[e];
            int c0 = t, c1 = t + 256;
            *(float4*)&vts[c0 >> 3][(c0 & 7) * 8] =
                *(const float4*)&qkv[(size_t)(b * SS + s0 + (c0 >> 3)) * 2304 + 1536 + h * 64 + (c0 & 7) * 8];
            *(float4*)&vts[c1 >> 3][(c1 & 7) * 8] =
                *(const float4*)&qkv[(size_t)(b * SS + s0 + (c1 >> 3)) * 2304 + 1536 + h * 64 + (c1 & 7) * 8];
        }
        __syncthreads();
#pragma unroll 4
        for (int sl = 0; sl < 64; ++sl) {
            float2 kk = *(const float2*)&kts[sl][f0];
            bf16x4 vv = *(const bf16x4*)&vts[sl][d0];
            float v0 = (float)vv[0], v1 = (float)vv[1], v2 = (float)vv[2], v3 = (float)vv[3];
            acc[0] += kk.x * v0; acc[1] += kk.x * v1; acc[2] += kk.x * v2; acc[3] += kk.x * v3;
            acc[4] += kk.y * v0; acc[5] += kk.y * v1; acc[6] += kk.y * v2; acc[7] += kk.y * v3;
            if (dg == 0) { ksm[0] += kk.x; ksm[1] += kk.y; }
        }
    }
    size_t base = (((size_t)(b * 12 + h) * 8 + ch) * 32) * 64;
#pragma unroll
    for (int i = 0; i < 2; ++i)
#pragma unroll
        for (int j = 0; j < 4; ++j)
            KVp[base + (size_t)(f0 + i) * 64 + d0 + j] = acc[i * 4 + j];
    if (dg == 0) {
        size_t kb = ((size_t)(b * 12 + h) * 8 + ch) * 32;
        Ksp[kb + f0] = ksm[0]; Ksp[kb + f0 + 1] = ksm[1];
    }
}

__global__ __launch_bounds__(256) void kvc_k(const float* __restrict__ KVp, const float* __restrict__ Ksp,
                                             float* __restrict__ KV, float* __restrict__ Ksum) {
    int bh = blockIdx.x, t = threadIdx.x;
    size_t base = (size_t)bh * 8 * 2048;
    float v[8] = {};
    for (int ch = 0; ch < 8; ++ch)
#pragma unroll
        for (int j = 0; j < 8; ++j) v[j] += KVp[base + (size_t)ch * 2048 + t * 8 + j];
#pragma unroll
    for (int j = 0; j < 8; ++j) KV[(size_t)bh * 2048 + t * 8 + j] = v[j];
    if (t < 32) {
        float s = 0.f;
        for (int ch = 0; ch < 8; ++ch) s += Ksp[((size_t)bh * 8 + ch) * 32 + t];
        Ksum[(size_t)bh * 32 + t] = s;
    }
}

// ---------------- combine: register-resident KV column; a = (Qf @ KV) / (Qf . Ksum + eps) ----------------
__global__ __launch_bounds__(256) void comb_k(const bf16* __restrict__ Qf, const float* __restrict__ KV,
                                              const float* __restrict__ Ksum, bf16* __restrict__ aout) {
    int ch = blockIdx.x, h = blockIdx.y, b = blockIdx.z;
    int bh = b * 12 + h;
    int t = threadIdx.x, sl = t >> 6, d = t & 63;
    const float* kvb = KV + (size_t)bh * 2048;
    const float* ksb = Ksum + (size_t)bh * 32;
    float kvcol[32], ksr[32];
#pragma unroll
    for (int f = 0; f < 32; ++f) kvcol[f] = kvb[f * 64 + d];
#pragma unroll
    for (int f = 0; f < 32; ++f) ksr[f] = ksb[f];
    for (int g = 0; g < 16; ++g) {
        int s = ch * 64 + g * 4 + sl;
        size_t tok = (size_t)b * SS + s;
        const bf16* qf = Qf + (tok * 12 + h) * 32;
        float accd = 0.f, accz = 0.f;
#pragma unroll
        for (int fb = 0; fb < 4; ++fb) {
            bf16x8 q8 = *(const bf16x8*)(qf + fb * 8);
#pragma unroll
            for (int e = 0; e < 8; ++e) {
                float q = (float)q8[e];
                accd += q * kvcol[fb * 8 + e];
                accz += q * ksr[fb * 8 + e];
            }
        }
        float z = 1.f / (accz + 1e-6f);
        aout[tok * 768 + h * 64 + d] = (bf16)(accd * z);
    }
}

// ---------------- LayerNorm of (x [+ y]) (row=768), f32 residual, vectorized, in-place ----------------
__global__ __launch_bounds__(192) void ln2_k(const float* xsrc, const bf16* ysrc,
                                             const float* __restrict__ g, const float* __restrict__ be,
                                             float* xout, bf16* xbout) {
    size_t tok = blockIdx.x;
    int t = threadIdx.x;
    float4 v = *(const float4*)&xsrc[tok * 768 + t * 4];
    if (ysrc) {
        bf16x4 yv = *(const bf16x4*)&ysrc[tok * 768 + t * 4];
        v.x += (float)yv[0]; v.y += (float)yv[1]; v.z += (float)yv[2]; v.w += (float)yv[3];
    }
    float s = v.x + v.y + v.z + v.w;
    float q = v.x * v.x + v.y * v.y + v.z * v.z + v.w * v.w;
#pragma unroll
    for (int off = 32; off > 0; off >>= 1) { s += __shfl_down(s, off); q += __shfl_down(q, off); }
    __shared__ float sred[3], qred[3];
    int w = t >> 6, lane = t & 63;
    if (lane == 0) { sred[w] = s; qred[w] = q; }
    __syncthreads();
    s = sred[0] + sred[1] + sred[2];
    q = qred[0] + qred[1] + qred[2];
    float mean = s * (1.f / 768.f);
    float var = q * (1.f / 768.f) - mean * mean;
    float inv = rsqrtf(var + 1e-5f);
    float4 gg = *(const float4*)&g[t * 4];
    float4 bb = *(const float4*)&be[t * 4];
    float4 o;
    o.x = (v.x - mean) * inv * gg.x + bb.x;
    o.y = (v.y - mean) * inv * gg.y + bb.y;
    o.z = (v.z - mean) * inv * gg.z + bb.z;
    o.w = (v.w - mean) * inv * gg.w + bb.w;
    *(float4*)&xout[tok * 768 + t * 4] = o;
    if (xbout) {
        bf16x4 ob; ob[0] = (bf16)o.x; ob[1] = (bf16)o.y; ob[2] = (bf16)o.z; ob[3] = (bf16)o.w;
        *(bf16x4*)&xbout[tok * 768 + t * 4] = ob;
    }
}

// ---------------- host ----------------
extern "C" void kernel_launch(void* const* d_in, const int* in_sizes, int n_in,
                              void* d_out, int out_size, void* d_ws, size_t ws_size,
                              hipStream_t stream) {
    const int*   idx   = (const int*)d_in[0];
    const int*   mask  = (const int*)d_in[1];
    const float* emb   = (const float*)d_in[2];
    const float* wq    = (const float*)d_in[3];
    const float* bq    = (const float*)d_in[4];
    const float* wk    = (const float*)d_in[5];
    const float* bk    = (const float*)d_in[6];
    const float* wv    = (const float*)d_in[7];
    const float* bv    = (const float*)d_in[8];
    const float* wo    = (const float*)d_in[9];
    const float* bo    = (const float*)d_in[10];
    const float* omega = (const float*)d_in[11];
    const float* g1    = (const float*)d_in[12];
    const float* be1   = (const float*)d_in[13];
    const float* w1    = (const float*)d_in[14];
    const float* c1    = (const float*)d_in[15];
    const float* w2    = (const float*)d_in[16];
    const float* c2    = (const float*)d_in[17];
    const float* g2    = (const float*)d_in[18];
    const float* be2   = (const float*)d_in[19];
    const float* gf    = (const float*)d_in[20];
    const float* bff   = (const float*)d_in[21];
    float* dout = (float*)d_out;

    char* wsb = (char*)d_ws;
    size_t off = 0;
    auto nxt = [&](size_t bytes) -> void* {
        void* p = wsb + off;
        off += bytes;
        off = (off + 255) & ~(size_t)255;
        return p;
    };

    float* cosT  = (float*)nxt((size_t)SS * 64 * 4);
    float* sinT  = (float*)nxt((size_t)SS * 64 * 4);
    bf16*  qkvTl = (bf16*)nxt((size_t)2304 * 768 * 2);
    bf16*  oTl   = (bf16*)nxt((size_t)768 * 768 * 2);
    bf16*  w1Tl  = (bf16*)nxt((size_t)768 * 768 * 2);
    bf16*  w2Tl  = (bf16*)nxt((size_t)768 * 768 * 2);
    float* bqkv  = (float*)nxt((size_t)NLL * 2304 * 4);
    float* x     = (float*)nxt((size_t)MTOK * 768 * 4);   // f32 residual (load-bearing)
    bf16*  xb    = (bf16*)nxt((size_t)MTOK * 768 * 2);
    bf16*  qkv   = (bf16*)nxt((size_t)MTOK * 2304 * 2);   // V region + abuf/h1/y overlays
    bf16*  Qf    = (bf16*)nxt((size_t)MTOK * 384 * 2);
    bf16*  Kf    = (bf16*)nxt((size_t)MTOK * 384 * 2);
    float* KVp   = (float*)nxt((size_t)NB * HH * 8 * 2048 * 4);
    float* Ksp   = (float*)nxt((size_t)NB * HH * 8 * 32 * 4);
    float* KV    = (float*)nxt((size_t)NB * HH * 2048 * 4);
    float* Ksum  = (float*)nxt((size_t)NB * HH * 32 * 4);
    size_t needed = off;                                  // ~375 MB

    if (ws_size < needed) {
        diag_k<<<dim3(1), dim3(64), 0, stream>>>(dout, 10000.f + (float)(ws_size >> 20));
        return;
    }

    // overlays into qkv buffer (q/k thirds unused; V dead after kvp_k): abuf | h1 | y
    bf16* abuf = qkv;
    bf16* h1   = (bf16*)((char*)qkv + (size_t)MTOK * 768 * 2);
    bf16* y    = (bf16*)((char*)qkv + (size_t)MTOK * 768 * 4);

    packb_k<<<dim3((NLL * 2304 + 255) / 256), dim3(256), 0, stream>>>(bq, bk, bv, bqkv);
    rope_k<<<dim3(SS * 64 / 256), dim3(256), 0, stream>>>(cosT, sinT);
    embed_k<<<dim3(MTOK), dim3(192), 0, stream>>>(idx, emb, x, xb);

    for (int l = 0; l < NLL; ++l) {
        const float* bqkv_l = bqkv + (size_t)l * 2304;
        const float* om_l   = omega + (size_t)l * 2048;

        packw_k<<<dim3(24, 24, 6), dim3(32, 8), 0, stream>>>(wq, wk, wv, wo, w1, w2, l, qkvTl, oTl, w1Tl, w2Tl);
        gemmqkv_k<<<dim3(18, 128), dim3(512), 0, stream>>>(xb, qkvTl, bqkv_l, cosT, sinT, om_l, mask,
                                                           qkv, Qf, Kf, 2304);
        kvp_k<<<dim3(8, HH, NB), dim3(256), 0, stream>>>(Kf, qkv, KVp, Ksp);
        kvc_k<<<dim3(NB * HH), dim3(256), 0, stream>>>(KVp, Ksp, KV, Ksum);
        comb_k<<<dim3(32, HH, NB), dim3(256), 0, stream>>>(Qf, KV, Ksum, abuf);
        gemm128_k<0><<<dim3(6, 256), dim3(256), 0, stream>>>(abuf, oTl, bo + (size_t)l * 768, y, 768);
        ln2_k<<<dim3(MTOK), dim3(192), 0, stream>>>(x, y, g1 + (size_t)l * 768, be1 + (size_t)l * 768, x, xb);
        gemm128_k<1><<<dim3(6, 256), dim3(256), 0, stream>>>(xb, w1Tl, c1 + (size_t)l * 768, h1, 768);
        gemm128_k<0><<<dim3(6, 256), dim3(256), 0, stream>>>(h1, w2Tl, c2 + (size_t)l * 768, y, 768);
        ln2_k<<<dim3(MTOK), dim3(192), 0, stream>>>(x, y, g2 + (size_t)l * 768, be2 + (size_t)l * 768, x,
                                                    (l == NLL - 1) ? nullptr : xb);
    }
    ln2_k<<<dim3(MTOK), dim3(192), 0, stream>>>(x, nullptr, gf, bff, dout, nullptr);
}

// Round 16
// 7245.176 us; speedup vs baseline: 1.5214x; 1.5214x over previous
//
#include <hip/hip_runtime.h>
#include <cstdint>
#include <cstddef>

typedef __bf16 bf16;
typedef __bf16 bf16x8 __attribute__((ext_vector_type(8)));
typedef __bf16 bf16x4 __attribute__((ext_vector_type(4)));
typedef float f32x4 __attribute__((ext_vector_type(4)));

#define NB 16
#define SS 2048
#define HH 12
#define NLL 12
#define MTOK (NB*SS)

#define BARRIER() do { asm volatile("" ::: "memory"); __builtin_amdgcn_s_barrier(); asm volatile("" ::: "memory"); } while (0)
#define VMCNT0()  asm volatile("s_waitcnt vmcnt(0)" ::: "memory")

// ---------------- async global->LDS (16B per lane) ----------------
__device__ __forceinline__ void load16_lds(const bf16* g, bf16* l) {
    __builtin_amdgcn_global_load_lds((const __attribute__((address_space(1))) void*)g,
                                     (__attribute__((address_space(3))) void*)l, 16, 0, 0);
}

// ---------------- diagnostic ----------------
__global__ void diag_k(float* out, float code) {
    if (threadIdx.x == 0 && blockIdx.x == 0) out[0] = code;
}

// ---------------- per-layer weight pack: f32 [K][N] -> bf16 [N][K] ----------------
__global__ __launch_bounds__(256) void packw_k(const float* __restrict__ wq, const float* __restrict__ wk,
                                               const float* __restrict__ wv, const float* __restrict__ wo,
                                               const float* __restrict__ w1, const float* __restrict__ w2,
                                               int l, bf16* qkvT_l, bf16* oT_l, bf16* w1T_l, bf16* w2T_l) {
    __shared__ float tile[32][33];
    int which = blockIdx.z;
    const float* srcs[6] = {wq, wk, wv, wo, w1, w2};
    const float* src = srcs[which] + (size_t)l * 589824;
    bf16* dst;
    if (which < 3)       dst = qkvT_l + (size_t)which * 589824;
    else if (which == 3) dst = oT_l;
    else if (which == 4) dst = w1T_l;
    else                 dst = w2T_l;
    int tx = threadIdx.x, ty = threadIdx.y;
    int bx = blockIdx.x, by = blockIdx.y;
#pragma unroll
    for (int j = 0; j < 4; ++j)
        tile[ty + j*8][tx] = src[(size_t)(by*32 + ty + j*8) * 768 + bx*32 + tx];
    __syncthreads();
#pragma unroll
    for (int j = 0; j < 4; ++j)
        dst[(size_t)(bx*32 + ty + j*8) * 768 + by*32 + tx] = (bf16)tile[tx][ty + j*8];
}

__global__ void packb_k(const float* __restrict__ bq, const float* __restrict__ bk,
                        const float* __restrict__ bv, float* bqkv) {
    int i = blockIdx.x * 256 + threadIdx.x;
    if (i >= NLL * 2304) return;
    int l = i / 2304, c = i % 2304;
    float v = (c < 768) ? bq[l*768 + c] : (c < 1536) ? bk[l*768 + c - 768] : bv[l*768 + c - 1536];
    bqkv[i] = v;
}

// ---------------- rope tables ----------------
__global__ void rope_k(float* cosT, float* sinT) {
    int i = blockIdx.x * 256 + threadIdx.x;  // S*64 total
    int s = i >> 6, j = i & 63, f = j & 31;
    float inv = powf(10000.f, -(float)(2*f) * (1.0f/64.0f));
    float ang = (float)s * inv;
    cosT[i] = cosf(ang);
    sinT[i] = sinf(ang);
}

// ---------------- embedding gather ----------------
__global__ __launch_bounds__(192) void embed_k(const int* __restrict__ idx, const float* __restrict__ emb,
                                               float* __restrict__ x, bf16* __restrict__ xb) {
    size_t tok = blockIdx.x;
    int t = threadIdx.x;
    int id = idx[tok];
    float4 v = *(const float4*)&emb[(size_t)id * 768 + t*4];
    *(float4*)&x[tok * 768 + t*4] = v;
    bf16x4 o; o[0] = (bf16)v.x; o[1] = (bf16)v.y; o[2] = (bf16)v.z; o[3] = (bf16)v.w;
    *(bf16x4*)&xb[tok * 768 + t*4] = o;
}

// ============ 256x256 GEMM (QKV): drain schedule + LDS-transposed coalesced epilogue ============
__global__ __launch_bounds__(512, 2)
void gemm256_k(const bf16* __restrict__ A, const bf16* __restrict__ Bt,
               const float* __restrict__ bias, bf16* __restrict__ outb, int N) {
    const int K = 768;
    __shared__ bf16 As[2][16384];   // [buf][256 rows x 64 cols]; epilogue reuses as 256x128 C-half
    __shared__ bf16 Bs[2][16384];
    const int t = threadIdx.x;
    const int w = t >> 6, lane = t & 63;
    const int wr = w >> 2, wc = w & 3;            // 2 x 4 wave grid

    const int nx = gridDim.x;
    const int L = blockIdx.y * nx + blockIdx.x;
    const int xcd = L & 7, bi = L >> 3;
    const int bcol = (bi % nx) * 256;
    const int brow = ((bi / nx) * 8 + xcd) * 256;

    const int srow0 = t >> 3;
    const int scb   = (t & 7) * 16;
    const int scbs  = scb ^ ((srow0 & 7) << 4);
    const int scol  = scbs >> 1;

    auto stageA = [&](int s, int k0, int hh) {
        const bf16* g0 = A + (size_t)(brow + hh*128 + srow0)      * K + k0 + scol;
        const bf16* g1 = A + (size_t)(brow + hh*128 + srow0 + 64) * K + k0 + scol;
        load16_lds(g0, &As[s][hh*8192 + t*8]);
        load16_lds(g1, &As[s][hh*8192 + t*8 + 4096]);
    };
    auto stageB = [&](int s, int k0, int hh) {
        const bf16* g0 = Bt + (size_t)(bcol + hh*128 + srow0)      * K + k0 + scol;
        const bf16* g1 = Bt + (size_t)(bcol + hh*128 + srow0 + 64) * K + k0 + scol;
        load16_lds(g0, &Bs[s][hh*8192 + t*8]);
        load16_lds(g1, &Bs[s][hh*8192 + t*8 + 4096]);
    };

    const int rowa = lane & 15, kg = lane >> 4;
    const int rsw  = (rowa & 7) << 4;

    f32x4  acc[8][4] = {};
    bf16x8 af[4][2];
    bf16x8 bg[2][2][2];

#define LOADAF(CUR, MH)                                                          \
    _Pragma("unroll") for (int mi2 = 0; mi2 < 4; ++mi2)                          \
    _Pragma("unroll") for (int ks = 0; ks < 2; ++ks) {                           \
        int lrow = wr*128 + (MH)*64 + mi2*16 + rowa;                             \
        int cbyt = (ks*64 + kg*16) ^ rsw;                                        \
        af[mi2][ks] = *(const bf16x8*)&As[CUR][lrow*64 + (cbyt >> 1)];           \
    }
#define LOADBG(CUR, NH)                                                          \
    _Pragma("unroll") for (int ni2 = 0; ni2 < 2; ++ni2)                          \
    _Pragma("unroll") for (int ks = 0; ks < 2; ++ks) {                           \
        int lrow = wc*64 + (NH)*32 + ni2*16 + rowa;                              \
        int cbyt = (ks*64 + kg*16) ^ rsw;                                        \
        bg[NH][ni2][ks] = *(const bf16x8*)&Bs[CUR][lrow*64 + (cbyt >> 1)];       \
    }
#define MFMAQ(MH, NH)                                                            \
    __builtin_amdgcn_s_setprio(1);                                               \
    _Pragma("unroll") for (int mi2 = 0; mi2 < 4; ++mi2)                          \
    _Pragma("unroll") for (int ni2 = 0; ni2 < 2; ++ni2)                          \
    _Pragma("unroll") for (int ks = 0; ks < 2; ++ks)                             \
        acc[(MH)*4+mi2][(NH)*2+ni2] = __builtin_amdgcn_mfma_f32_16x16x32_bf16(   \
            af[mi2][ks], bg[NH][ni2][ks], acc[(MH)*4+mi2][(NH)*2+ni2], 0, 0, 0); \
    __builtin_amdgcn_s_setprio(0);

    stageA(0, 0, 0); stageA(0, 0, 1); stageB(0, 0, 0); stageB(0, 0, 1);
    VMCNT0();
    BARRIER();

    for (int kt = 0; kt < 12; ++kt) {
        const int cur = kt & 1, nb = cur ^ 1;
        const int kn = (kt + 1) * 64;
        const bool st = (kt < 11);
        LOADAF(cur, 0);
        LOADBG(cur, 0);
        if (st) { stageA(nb, kn, 0); stageA(nb, kn, 1); }
        BARRIER();
        MFMAQ(0, 0);
        BARRIER();
        LOADBG(cur, 1);
        if (st) stageB(nb, kn, 0);
        BARRIER();
        MFMAQ(0, 1);
        BARRIER();
        LOADAF(cur, 1);
        if (st) stageB(nb, kn, 1);
        BARRIER();
        MFMAQ(1, 1);
        BARRIER();
        MFMAQ(1, 0);
        VMCNT0();
        BARRIER();
    }
#undef LOADAF
#undef LOADBG
#undef MFMAQ

    // ---- epilogue: C via LDS, coalesced 16B stores (two 256x128 halves) ----
    bf16* Cs = &As[0][0];                      // 64 KB: 256 rows x 128 cols
    const int r0 = (lane >> 4) * 4, c0 = lane & 15;
    const int ch = t & 15, rr = t >> 4;        // store-phase: chunk, row-group
#pragma unroll
    for (int h = 0; h < 2; ++h) {
        __syncthreads();
        if ((wc >> 1) == h) {
            const int lc0 = (wc & 1) * 64;
#pragma unroll
            for (int mi = 0; mi < 8; ++mi)
#pragma unroll
                for (int ni = 0; ni < 4; ++ni) {
                    int col = bcol + wc * 64 + ni * 16 + c0;
                    float bv = bias[col];
#pragma unroll
                    for (int r = 0; r < 4; ++r)
                        Cs[(wr*128 + mi*16 + r0 + r) * 128 + lc0 + ni*16 + c0] =
                            (bf16)(acc[mi][ni][r] + bv);
                }
        }
        __syncthreads();
#pragma unroll
        for (int i = 0; i < 8; ++i) {
            int row = rr + i * 32;
            *(bf16x8*)&outb[(size_t)(brow + row) * N + bcol + h*128 + ch*8] =
                *(const bf16x8*)&Cs[row * 128 + ch * 8];
        }
    }
}

// ============ 128x128 GEMM, BK=64 + T2 swizzle + LDS-transposed epilogue ============
// MODE 0: +bias -> bf16; MODE 1: +bias, gelu -> bf16
template <int MODE>
__global__ __launch_bounds__(256)
void gemm128_k(const bf16* __restrict__ A, const bf16* __restrict__ Bt,
               const float* __restrict__ bias, bf16* __restrict__ outb, int N) {
    const int K = 768;
    __shared__ bf16 sh[16384];                 // As=sh[0..8191], Bs=sh[8192..]; epilogue: C 128x128
    bf16* As = sh;
    bf16* Bs = sh + 8192;
    const int t = threadIdx.x;
    const int w = t >> 6, lane = t & 63;
    const int wr = w >> 1, wc = w & 1;

    const int nx = gridDim.x;
    const int L = blockIdx.y * nx + blockIdx.x;
    const int xcd = L & 7, bi = L >> 3;
    const int bcol = (bi % nx) * 128;
    const int brow = ((bi / nx) * 8 + xcd) * 128;

    const int srow = t >> 3;
    const int scol = (((t & 7) * 16) ^ ((srow & 7) << 4)) >> 1;
    const int rowa = lane & 15, kg = lane >> 4;
    const int rsw  = (rowa & 7) << 4;

    f32x4 acc[4][4] = {};

    for (int k0 = 0; k0 < K; k0 += 64) {
        __syncthreads();
#pragma unroll
        for (int j = 0; j < 4; ++j) {
            load16_lds(A  + (size_t)(brow + j*32 + srow) * K + k0 + scol, &As[j*2048 + t*8]);
            load16_lds(Bt + (size_t)(bcol + j*32 + srow) * K + k0 + scol, &Bs[j*2048 + t*8]);
        }
        __syncthreads();
        bf16x8 af[4][2], bg[4][2];
#pragma unroll
        for (int mi = 0; mi < 4; ++mi)
#pragma unroll
            for (int ks = 0; ks < 2; ++ks)
                af[mi][ks] = *(const bf16x8*)&As[(wr*64 + mi*16 + rowa)*64 + (((ks*64 + kg*16) ^ rsw) >> 1)];
#pragma unroll
        for (int ni = 0; ni < 4; ++ni)
#pragma unroll
            for (int ks = 0; ks < 2; ++ks)
                bg[ni][ks] = *(const bf16x8*)&Bs[(wc*64 + ni*16 + rowa)*64 + (((ks*64 + kg*16) ^ rsw) >> 1)];
#pragma unroll
        for (int mi = 0; mi < 4; ++mi)
#pragma unroll
            for (int ni = 0; ni < 4; ++ni)
#pragma unroll
                for (int ks = 0; ks < 2; ++ks)
                    acc[mi][ni] = __builtin_amdgcn_mfma_f32_16x16x32_bf16(af[mi][ks], bg[ni][ks], acc[mi][ni], 0, 0, 0);
    }

    // ---- epilogue: C via LDS, coalesced 16B stores ----
    __syncthreads();                           // last-tile fragment reads done before C overwrite
    const int r0 = (lane >> 4) * 4, c0 = lane & 15;
#pragma unroll
    for (int mi = 0; mi < 4; ++mi)
#pragma unroll
        for (int ni = 0; ni < 4; ++ni) {
            int col = bcol + wc * 64 + ni * 16 + c0;
            float bv = bias[col];
#pragma unroll
            for (int r = 0; r < 4; ++r) {
                float v = acc[mi][ni][r] + bv;
                if (MODE == 1) v = 0.5f * v * (1.f + erff(v * 0.70710678118f));
                sh[(wr*64 + mi*16 + r0 + r) * 128 + wc*64 + ni*16 + c0] = (bf16)v;
            }
        }
    __syncthreads();
    const int ch = t & 15, rr = t >> 4;
#pragma unroll
    for (int i = 0; i < 8; ++i) {
        int row = rr + i * 16;
        *(bf16x8*)&outb[(size_t)(brow + row) * N + bcol + ch*8] =
            *(const bf16x8*)&sh[row * 128 + ch * 8];
    }
}

// ---------------- rope + feature map: Qf/Kf = relu(rope(q/k) @ omega), bf16 out ----------------
__global__ __launch_bounds__(192) void phi_k(const bf16* __restrict__ qkv, const float* __restrict__ cosT,
                                             const float* __restrict__ sinT, const float* __restrict__ omega_l,
                                             const int* __restrict__ mask, bf16* __restrict__ Qf,
                                             bf16* __restrict__ Kf) {
    __shared__ float roped[2][4][12][65];
    __shared__ float om[64][32];
    int t = threadIdx.x;
    size_t tok0 = (size_t)blockIdx.x * 4;

    for (int i = t; i < 2048; i += 192) ((float*)om)[i] = omega_l[i];

    {
        int side = t / 96, cr = t % 96, h = cr >> 3, cq = cr & 7;
        float sgn = (cq < 4) ? -1.f : 1.f;
        for (int it = 0; it < 4; ++it) {
            size_t tokg = tok0 + it;
            int s = (int)(tokg & (SS - 1));
            const bf16* rowp = qkv + tokg * 2304 + side * 768 + h * 64;
            bf16x8 mv = *(const bf16x8*)(rowp + cq * 8);
            bf16x8 pv = *(const bf16x8*)(rowp + (cq ^ 4) * 8);
            const float* cp = cosT + s * 64 + cq * 8;
            const float* sp = sinT + s * 64 + cq * 8;
#pragma unroll
            for (int e = 0; e < 8; ++e) {
                float r = (float)mv[e] * cp[e] + sgn * (float)pv[e] * sp[e];
                roped[side][it][h][cq * 8 + e] = r;
            }
        }
    }
    __syncthreads();

    int side = t / 96, rr = t % 96, h = rr >> 3, f0 = (rr & 7) * 4;
    float acc[4][4] = {};
    for (int d = 0; d < 64; ++d) {
        float4 o = *(const float4*)&om[d][f0];
#pragma unroll
        for (int tk = 0; tk < 4; ++tk) {
            float qv = roped[side][tk][h][d];
            acc[tk][0] += qv * o.x; acc[tk][1] += qv * o.y;
            acc[tk][2] += qv * o.z; acc[tk][3] += qv * o.w;
        }
    }
    bf16* outb = (side == 0) ? Qf : Kf;
#pragma unroll
    for (int tk = 0; tk < 4; ++tk) {
        size_t tokg = tok0 + tk;
        float m = (side == 1) ? (float)mask[tokg] : 1.f;
        bf16x4 v;
        v[0] = (bf16)(fmaxf(acc[tk][0], 0.f) * m);
        v[1] = (bf16)(fmaxf(acc[tk][1], 0.f) * m);
        v[2] = (bf16)(fmaxf(acc[tk][2], 0.f) * m);
        v[3] = (bf16)(fmaxf(acc[tk][3], 0.f) * m);
        *(bf16x4*)&outb[(tokg * 12 + h) * 32 + f0] = v;
    }
}

// ---------------- KV partial: per (b,h,chunk) sum_s Kf[s,f]*v[s,d]; also sum Kf ----------------
__global__ __launch_bounds__(256) void kvp_k(const bf16* __restrict__ Kf, const bf16* __restrict__ qkv,
                                             float* __restrict__ KVp, float* __restrict__ Ksp) {
    int ch = blockIdx.x, h = blockIdx.y, b = blockIdx.z;
    __shared__ float kts[64][32];
    __shared__ bf16 vts[64][64];
    int t = threadIdx.x;
    int fg = t & 15, dg = t >> 4;
    int f0 = fg * 2, d0 = dg * 4;
    float acc[8] = {};
    float ksm[2] = {};
    for (int s0 = ch * 256; s0 < ch * 256 + 256; s0 += 64) {
        __syncthreads();
        {
            int row = t >> 2, slot = t & 3;
            bf16x8 k8 = *(const bf16x8*)&Kf[((size_t)(b * SS + s0 + row) * 12 + h) * 32 + slot * 8];
#pragma unroll
            for (int e = 0; e < 8; ++e) kts[row][slot * 8 + e] = (float)k8[e];
            int c0 = t, c1 = t + 256;
            *(float4*)&vts[c0 >> 3][(c0 & 7) * 8] =
                *(const float4*)&qkv[(size_t)(b * SS + s0 + (c0 >> 3)) * 2304 + 1536 + h * 64 + (c0 & 7) * 8];
            *(float4*)&vts[c1 >> 3][(c1 & 7) * 8] =
                *(const float4*)&qkv[(size_t)(b * SS + s0 + (c1 >> 3)) * 2304 + 1536 + h * 64 + (c1 & 7) * 8];
        }
        __syncthreads();
#pragma unroll 4
        for (int sl = 0; sl < 64; ++sl) {
            float2 kk = *(const float2*)&kts[sl][f0];
            bf16x4 vv = *(const bf16x4*)&vts[sl][d0];
            float v0 = (float)vv[0], v1 = (float)vv[1], v2 = (float)vv[2], v3 = (float)vv[3];
            acc[0] += kk.x * v0; acc[1] += kk.x * v1; acc[2] += kk.x * v2; acc[3] += kk.x * v3;
            acc[4] += kk.y * v0; acc[5] += kk.y * v1; acc[6] += kk.y * v2; acc[7] += kk.y * v3;
            if (dg == 0) { ksm[0] += kk.x; ksm[1] += kk.y; }
        }
    }
    size_t base = (((size_t)(b * 12 + h) * 8 + ch) * 32) * 64;
#pragma unroll
    for (int i = 0; i < 2; ++i)
#pragma unroll
        for (int j = 0; j < 4; ++j)
            KVp[base + (size_t)(f0 + i) * 64 + d0 + j] = acc[i * 4 + j];
    if (dg == 0) {
        size_t kb = ((size_t)(b * 12 + h) * 8 + ch) * 32;
        Ksp[kb + f0] = ksm[0]; Ksp[kb + f0 + 1] = ksm[1];
    }
}

__global__ __launch_bounds__(256) void kvc_k(const float* __restrict__ KVp, const float* __restrict__ Ksp,
                                             float* __restrict__ KV, float* __restrict__ Ksum) {
    int bh = blockIdx.x, t = threadIdx.x;
    size_t base = (size_t)bh * 8 * 2048;
    float v[8] = {};
    for (int ch = 0; ch < 8; ++ch)
#pragma unroll
        for (int j = 0; j < 8; ++j) v[j] += KVp[base + (size_t)ch * 2048 + t * 8 + j];
#pragma unroll
    for (int j = 0; j < 8; ++j) KV[(size_t)bh * 2048 + t * 8 + j] = v[j];
    if (t < 32) {
        float s = 0.f;
        for (int ch = 0; ch < 8; ++ch) s += Ksp[((size_t)bh * 8 + ch) * 32 + t];
        Ksum[(size_t)bh * 32 + t] = s;
    }
}

// ---------------- combine: register-resident KV column; a = (Qf @ KV) / (Qf . Ksum + eps) ----------------
__global__ __launch_bounds__(256) void comb_k(const bf16* __restrict__ Qf, const float* __restrict__ KV,
                                              const float* __restrict__ Ksum, bf16* __restrict__ aout) {
    int ch = blockIdx.x, h = blockIdx.y, b = blockIdx.z;
    int bh = b * 12 + h;
    int t = threadIdx.x, sl = t >> 6, d = t & 63;
    const float* kvb = KV + (size_t)bh * 2048;
    const float* ksb = Ksum + (size_t)bh * 32;
    float kvcol[32], ksr[32];
#pragma unroll
    for (int f = 0; f < 32; ++f) kvcol[f] = kvb[f * 64 + d];
#pragma unroll
    for (int f = 0; f < 32; ++f) ksr[f] = ksb[f];
    for (int g = 0; g < 16; ++g) {
        int s = ch * 64 + g * 4 + sl;
        size_t tok = (size_t)b * SS + s;
        const bf16* qf = Qf + (tok * 12 + h) * 32;
        float accd = 0.f, accz = 0.f;
#pragma unroll
        for (int fb = 0; fb < 4; ++fb) {
            bf16x8 q8 = *(const bf16x8*)(qf + fb * 8);
#pragma unroll
            for (int e = 0; e < 8; ++e) {
                float q = (float)q8[e];
                accd += q * kvcol[fb * 8 + e];
                accz += q * ksr[fb * 8 + e];
            }
        }
        float z = 1.f / (accz + 1e-6f);
        aout[tok * 768 + h * 64 + d] = (bf16)(accd * z);
    }
}

// ---------------- LayerNorm of (x [+ y]) (row=768), f32 residual, vectorized, in-place ----------------
__global__ __launch_bounds__(192) void ln2_k(const float* xsrc, const bf16* ysrc,
                                             const float* __restrict__ g, const float* __restrict__ be,
                                             float* xout, bf16* xbout) {
    size_t tok = blockIdx.x;
    int t = threadIdx.x;
    float4 v = *(const float4*)&xsrc[tok * 768 + t * 4];
    if (ysrc) {
        bf16x4 yv = *(const bf16x4*)&ysrc[tok * 768 + t * 4];
        v.x += (float)yv[0]; v.y += (float)yv[1]; v.z += (float)yv[2]; v.w += (float)yv[3];
    }
    float s = v.x + v.y + v.z + v.w;
    float q = v.x * v.x + v.y * v.y + v.z * v.z + v.w * v.w;
#pragma unroll
    for (int off = 32; off > 0; off >>= 1) { s += __shfl_down(s, off); q += __shfl_down(q, off); }
    __shared__ float sred[3], qred[3];
    int w = t >> 6, lane = t & 63;
    if (lane == 0) { sred[w] = s; qred[w] = q; }
    __syncthreads();
    s = sred[0] + sred[1] + sred[2];
    q = qred[0] + qred[1] + qred[2];
    float mean = s * (1.f / 768.f);
    float var = q * (1.f / 768.f) - mean * mean;
    float inv = rsqrtf(var + 1e-5f);
    float4 gg = *(const float4*)&g[t * 4];
    float4 bb = *(const float4*)&be[t * 4];
    float4 o;
    o.x = (v.x - mean) * inv * gg.x + bb.x;
    o.y = (v.y - mean) * inv * gg.y + bb.y;
    o.z = (v.z - mean) * inv * gg.z + bb.z;
    o.w = (v.w - mean) * inv * gg.w + bb.w;
    *(float4*)&xout[tok * 768 + t * 4] = o;
    if (xbout) {
        bf16x4 ob; ob[0] = (bf16)o.x; ob[1] = (bf16)o.y; ob[2] = (bf16)o.z; ob[3] = (bf16)o.w;
        *(bf16x4*)&xbout[tok * 768 + t * 4] = ob;
    }
}

// ---------------- host ----------------
extern "C" void kernel_launch(void* const* d_in, const int* in_sizes, int n_in,
                              void* d_out, int out_size, void* d_ws, size_t ws_size,
                              hipStream_t stream) {
    const int*   idx   = (const int*)d_in[0];
    const int*   mask  = (const int*)d_in[1];
    const float* emb   = (const float*)d_in[2];
    const float* wq    = (const float*)d_in[3];
    const float* bq    = (const float*)d_in[4];
    const float* wk    = (const float*)d_in[5];
    const float* bk    = (const float*)d_in[6];
    const float* wv    = (const float*)d_in[7];
    const float* bv    = (const float*)d_in[8];
    const float* wo    = (const float*)d_in[9];
    const float* bo    = (const float*)d_in[10];
    const float* omega = (const float*)d_in[11];
    const float* g1    = (const float*)d_in[12];
    const float* be1   = (const float*)d_in[13];
    const float* w1    = (const float*)d_in[14];
    const float* c1    = (const float*)d_in[15];
    const float* w2    = (const float*)d_in[16];
    const float* c2    = (const float*)d_in[17];
    const float* g2    = (const float*)d_in[18];
    const float* be2   = (const float*)d_in[19];
    const float* gf    = (const float*)d_in[20];
    const float* bff   = (const float*)d_in[21];
    float* dout = (float*)d_out;

    char* wsb = (char*)d_ws;
    size_t off = 0;
    auto nxt = [&](size_t bytes) -> void* {
        void* p = wsb + off;
        off += bytes;
        off = (off + 255) & ~(size_t)255;
        return p;
    };

    float* cosT  = (float*)nxt((size_t)SS * 64 * 4);
    float* sinT  = (float*)nxt((size_t)SS * 64 * 4);
    bf16*  qkvTl = (bf16*)nxt((size_t)2304 * 768 * 2);
    bf16*  oTl   = (bf16*)nxt((size_t)768 * 768 * 2);
    bf16*  w1Tl  = (bf16*)nxt((size_t)768 * 768 * 2);
    bf16*  w2Tl  = (bf16*)nxt((size_t)768 * 768 * 2);
    float* bqkv  = (float*)nxt((size_t)NLL * 2304 * 4);
    float* x     = (float*)nxt((size_t)MTOK * 768 * 4);   // f32 residual (load-bearing)
    bf16*  xb    = (bf16*)nxt((size_t)MTOK * 768 * 2);
    bf16*  qkv   = (bf16*)nxt((size_t)MTOK * 2304 * 2);   // hosts abuf/h1/y overlays later
    bf16*  Qf    = (bf16*)nxt((size_t)MTOK * 384 * 2);
    bf16*  Kf    = (bf16*)nxt((size_t)MTOK * 384 * 2);
    float* KVp   = (float*)nxt((size_t)NB * HH * 8 * 2048 * 4);
    float* Ksp   = (float*)nxt((size_t)NB * HH * 8 * 32 * 4);
    float* KV    = (float*)nxt((size_t)NB * HH * 2048 * 4);
    float* Ksum  = (float*)nxt((size_t)NB * HH * 32 * 4);
    size_t needed = off;                                  // ~375 MB

    if (ws_size < needed) {
        diag_k<<<dim3(1), dim3(64), 0, stream>>>(dout, 10000.f + (float)(ws_size >> 20));
        return;
    }

    // overlays into qkv buffer (dead after kvp_k): abuf | h1 | y, 50.3 MB each
    bf16* abuf = qkv;
    bf16* h1   = (bf16*)((char*)qkv + (size_t)MTOK * 768 * 2);
    bf16* y    = (bf16*)((char*)qkv + (size_t)MTOK * 768 * 4);

    packb_k<<<dim3((NLL * 2304 + 255) / 256), dim3(256), 0, stream>>>(bq, bk, bv, bqkv);
    rope_k<<<dim3(SS * 64 / 256), dim3(256), 0, stream>>>(cosT, sinT);
    embed_k<<<dim3(MTOK), dim3(192), 0, stream>>>(idx, emb, x, xb);

    for (int l = 0; l < NLL; ++l) {
        const float* bqkv_l = bqkv + (size_t)l * 2304;
        const float* om_l   = omega + (size_t)l * 2048;

        packw_k<<<dim3(24, 24, 6), dim3(32, 8), 0, stream>>>(wq, wk, wv, wo, w1, w2, l, qkvTl, oTl, w1Tl, w2Tl);
        gemm256_k<<<dim3(9, 128), dim3(512), 0, stream>>>(xb, qkvTl, bqkv_l, qkv, 2304);
        phi_k<<<dim3(MTOK / 4), dim3(192), 0, stream>>>(qkv, cosT, sinT, om_l, mask, Qf, Kf);
        kvp_k<<<dim3(8, HH, NB), dim3(256), 0, stream>>>(Kf, qkv, KVp, Ksp);
        kvc_k<<<dim3(NB * HH), dim3(256), 0, stream>>>(KVp, Ksp, KV, Ksum);
        comb_k<<<dim3(32, HH, NB), dim3(256), 0, stream>>>(Qf, KV, Ksum, abuf);
        gemm128_k<0><<<dim3(6, 256), dim3(256), 0, stream>>>(abuf, oTl, bo + (size_t)l * 768, y, 768);
        ln2_k<<<dim3(MTOK), dim3(192), 0, stream>>>(x, y, g1 + (size_t)l * 768, be1 + (size_t)l * 768, x, xb);
        gemm128_k<1><<<dim3(6, 256), dim3(256), 0, stream>>>(xb, w1Tl, c1 + (size_t)l * 768, h1, 768);
        gemm128_k<0><<<dim3(6, 256), dim3(256), 0, stream>>>(h1, w2Tl, c2 + (size_t)l * 768, y, 768);
        ln2_k<<<dim3(MTOK), dim3(192), 0, stream>>>(x, y, g2 + (size_t)l * 768, be2 + (size_t)l * 768, x,
                                                    (l == NLL - 1) ? nullptr : xb);
    }
    ln2_k<<<dim3(MTOK), dim3(192), 0, stream>>>(x, nullptr, gf, bff, dout, nullptr);
}